// Round 9
// baseline (1360.142 us; speedup 1.0000x reference)
//
#include <hip/hip_runtime.h>
#include <math.h>

// Block-circulant SwiGLU FFN via per-wave radix-8 FFT-512 (CirCNN style).
// d_model=2048 (p=4 blocks), d_ff=5632 (q=11 blocks), BLOCK=512.
// Round-9: R8 one-wave-per-row structure + VGPR diet to re-cross the 128
// cliff (R8's 136 VGPR -> 2 waves/SIMD was the regression):
//   * Z accumulator [4][5] -> [4][4]: Nyquist (k=256, real) packed into the
//     imaginary slot of k=0 (also real). -8 VGPR.
//   * __launch_bounds__(64, 4) pins the allocation at <=128.
// Fenceless FFT: same-wave DS ops are in-order (HW-verified R4/R7).

// LDS element-index swizzle: every access pattern used here is GF(2)-linear
// rank-4 in lane bits -> uniform 4 lanes per bank pair (b64 minimum).
__device__ __forceinline__ int swz(int n) { return n ^ ((n >> 3) & 15); }

struct Tw { float t0r[7], t0i[7], t1r[7], t1i[7]; };

// Per-lane register twiddles: stage0 W512^{l*m}, stage1 W512^{8*(l>>3)*m}.
__device__ __forceinline__ void make_tw(int l, Tw& T)
{
    float c0, s0;
    __sincosf(-6.283185307179586f * (float)l * (1.0f/512.0f), &s0, &c0);
    float pr = c0, pi = s0;
    T.t0r[0] = pr; T.t0i[0] = pi;
#pragma unroll
    for (int m = 1; m < 7; ++m) {
        float nr = pr*c0 - pi*s0, ni = pr*s0 + pi*c0;
        pr = nr; pi = ni;
        T.t0r[m] = pr; T.t0i[m] = pi;
    }
    float c1, s1;
    __sincosf(-6.283185307179586f * (float)(l >> 3) * (1.0f/64.0f), &s1, &c1);
    pr = c1; pi = s1;
    T.t1r[0] = pr; T.t1i[0] = pi;
#pragma unroll
    for (int m = 1; m < 7; ++m) {
        float nr = pr*c1 - pi*s1, ni = pr*s1 + pi*c1;
        pr = nr; pi = ni;
        T.t1r[m] = pr; T.t1i[m] = pi;
    }
}

// 8-point DFT (DIF): A_m = sum_q a_q w8^{qm}, w8 = e^{-2pi i/8} (conj if INV).
template<bool INV>
__device__ __forceinline__ void dft8(float xr[8], float xi[8])
{
    const float C = 0.70710678118654752f;
    float tr[4], ti[4], ur[4], ui[4];
#pragma unroll
    for (int q = 0; q < 4; ++q) {
        tr[q] = xr[q] + xr[q+4];  ti[q] = xi[q] + xi[q+4];
        ur[q] = xr[q] - xr[q+4];  ui[q] = xi[q] - xi[q+4];
    }
    {
        float xx = ur[1], yy = ui[1];
        if (!INV) { ur[1] = C*(xx+yy); ui[1] = C*(yy-xx); }
        else      { ur[1] = C*(xx-yy); ui[1] = C*(xx+yy); }
    }
    {
        float xx = ur[2], yy = ui[2];
        if (!INV) { ur[2] = yy;  ui[2] = -xx; }
        else      { ur[2] = -yy; ui[2] = xx; }
    }
    {
        float xx = ur[3], yy = ui[3];
        if (!INV) { ur[3] = C*(yy-xx);  ui[3] = -C*(xx+yy); }
        else      { ur[3] = -C*(xx+yy); ui[3] = C*(xx-yy); }
    }
    {
        float s0r=tr[0]+tr[2], s0i=ti[0]+ti[2];
        float d0r=tr[0]-tr[2], d0i=ti[0]-ti[2];
        float s1r=tr[1]+tr[3], s1i=ti[1]+ti[3];
        float e1r=tr[1]-tr[3], e1i=ti[1]-ti[3];
        float d1r, d1i;
        if (!INV) { d1r = e1i;  d1i = -e1r; } else { d1r = -e1i; d1i = e1r; }
        xr[0]=s0r+s1r; xi[0]=s0i+s1i;
        xr[2]=d0r+d1r; xi[2]=d0i+d1i;
        xr[4]=s0r-s1r; xi[4]=s0i-s1i;
        xr[6]=d0r-d1r; xi[6]=d0i-d1i;
    }
    {
        float s0r=ur[0]+ur[2], s0i=ui[0]+ui[2];
        float d0r=ur[0]-ur[2], d0i=ui[0]-ui[2];
        float s1r=ur[1]+ur[3], s1i=ui[1]+ui[3];
        float e1r=ur[1]-ur[3], e1i=ui[1]-ui[3];
        float d1r, d1i;
        if (!INV) { d1r = e1i;  d1i = -e1r; } else { d1r = -e1i; d1i = e1r; }
        xr[1]=s0r+s1r; xi[1]=s0i+s1i;
        xr[3]=d0r+d1r; xi[3]=d0i+d1i;
        xr[5]=s0r-s1r; xi[5]=s0i-s1i;
        xr[7]=d0r-d1r; xi[7]=d0i-d1i;
    }
}

// In-place radix-8 Stockham FFT-512 on a wave-private (swizzled) LDS buffer.
// Natural-order in/out; forward = e^{-i}, INV = conjugated (unscaled inverse).
template<bool INV>
__device__ __forceinline__ void fft512_r8(float2* wk, int l, const Tw& T)
{
    float xr[8], xi[8];
    // ---- stage 0 (s=1): twiddle W^{l*m} ----
#pragma unroll
    for (int q = 0; q < 8; ++q) { float2 v = wk[swz(l + 64*q)]; xr[q]=v.x; xi[q]=v.y; }
    dft8<INV>(xr, xi);
#pragma unroll
    for (int m = 1; m < 8; ++m) {
        float wr = T.t0r[m-1], wi = INV ? -T.t0i[m-1] : T.t0i[m-1];
        float nr = xr[m]*wr - xi[m]*wi, ni = xr[m]*wi + xi[m]*wr;
        xr[m]=nr; xi[m]=ni;
    }
#pragma unroll
    for (int m = 0; m < 8; ++m) wk[swz(8*l + m)] = make_float2(xr[m], xi[m]);
    // ---- stage 1 (s=8): twiddle W^{8*(l>>3)*m} ----
#pragma unroll
    for (int q = 0; q < 8; ++q) { float2 v = wk[swz(l + 64*q)]; xr[q]=v.x; xi[q]=v.y; }
    dft8<INV>(xr, xi);
#pragma unroll
    for (int m = 1; m < 8; ++m) {
        float wr = T.t1r[m-1], wi = INV ? -T.t1i[m-1] : T.t1i[m-1];
        float nr = xr[m]*wr - xi[m]*wi, ni = xr[m]*wi + xi[m]*wr;
        xr[m]=nr; xi[m]=ni;
    }
    {
        const int base = 64*(l>>3) + (l&7);
#pragma unroll
        for (int m = 0; m < 8; ++m) wk[swz(base + 8*m)] = make_float2(xr[m], xi[m]);
    }
    // ---- stage 2 (s=64): no twiddle ----
#pragma unroll
    for (int q = 0; q < 8; ++q) { float2 v = wk[swz(l + 64*q)]; xr[q]=v.x; xi[q]=v.y; }
    dft8<INV>(xr, xi);
#pragma unroll
    for (int m = 0; m < 8; ++m) wk[swz(l + 64*m)] = make_float2(xr[m], xi[m]);
}

// ---------------- weight spectra precompute: one wave per weight block ----------------
// wsp (float2): blocks 0..43 = rfft(wg)/512 (idx q*4+p), 44..87 = rfft(wu)/512,
// 88..131 = rfft(wd)/512 (idx p*11+q). 257 entries per block.
__global__ __launch_bounds__(64) void wf_prep(const float* __restrict__ wg,
                                              const float* __restrict__ wu,
                                              const float* __restrict__ wd,
                                              float2* __restrict__ wsp)
{
    __shared__ float2 wk[512];
    const int t = threadIdx.x;
    Tw T; make_tw(t, T);
    const int b = blockIdx.x;      // 0..131
    const float* src = (b < 44) ? (wg + (size_t)b * 512)
                     : (b < 88) ? (wu + (size_t)(b - 44) * 512)
                                : (wd + (size_t)(b - 88) * 512);
    float2* dst = wsp + (size_t)b * 257;

#pragma unroll
    for (int i = 0; i < 8; ++i) { int n = t + 64*i; wk[swz(n)] = make_float2(src[n], 0.f); }
    fft512_r8<false>(wk, t, T);
    const float sc = 1.0f / 512.0f;   // fold irfft 1/N into the weight spectrum
#pragma unroll
    for (int i = 0; i < 5; ++i) {
        int k = t + 64*i;
        if (k <= 256) { float2 z = wk[swz(k)]; dst[k] = make_float2(sc*z.x, sc*z.y); }
    }
}

// ---------------- fused FFN: ONE 64-thread block (one wave) per row ----------------
__global__ __launch_bounds__(64, 4) void bcffn(const float* __restrict__ x,
                                               const float2* __restrict__ wsp,
                                               float* __restrict__ out)
{
    __shared__ float2 wk[512];        //  4 KB   FFT work buffer (swizzled)
    __shared__ float2 sXf[4][257];    //  8.2 KB X spectra (half, Hermitian)

    const int t = threadIdx.x;
    const size_t row = blockIdx.x;

    Tw T; make_tw(t, T);

    const float2* Wg = wsp;
    const float2* Wu = wsp + 44 * 257;
    const float2* Wd = wsp + 88 * 257;

    // ---- P1: two packed FFTs: (x block 0 + i x block 1), (block 2 + i block 3) ----
#pragma unroll 1
    for (int h = 0; h < 2; ++h) {
        const float4* xa = (const float4*)(x + row * 2048 + (size_t)(2*h)   * 512);
        const float4* xb = (const float4*)(x + row * 2048 + (size_t)(2*h+1) * 512);
#pragma unroll
        for (int u = 0; u < 2; ++u) {
            int e = t + 64*u;
            float4 a = xa[e], b = xb[e];
            int n = 4*e;
            wk[swz(n+0)] = make_float2(a.x, b.x);
            wk[swz(n+1)] = make_float2(a.y, b.y);
            wk[swz(n+2)] = make_float2(a.z, b.z);
            wk[swz(n+3)] = make_float2(a.w, b.w);
        }
        fft512_r8<false>(wk, t, T);
#pragma unroll
        for (int u = 0; u < 5; ++u) {
            int k = t + 64*u;
            if (k <= 256) {
                float2 z = wk[swz(k)], m = wk[swz((512 - k) & 511)];
                sXf[2*h][k]   = make_float2(0.5f*(z.x + m.x), 0.5f*(z.y - m.y));
                sXf[2*h+1][k] = make_float2(0.5f*(z.y + m.y), 0.5f*(m.x - z.x));
            }
        }
    }

    // einsum for block-row q: packed spectrum Z = G + i*U into wk (all 512)
    auto einsum_gu = [&](int q) {
#pragma unroll
        for (int u = 0; u < 5; ++u) {
            int k = t + 64*u;
            if (k <= 256) {
                float gr=0.f, gi=0.f, ur_=0.f, ui_=0.f;
#pragma unroll
                for (int p = 0; p < 4; ++p) {
                    float2 X = sXf[p][k];
                    float2 a = Wg[(q*4 + p)*257 + k];
                    float2 b = Wu[(q*4 + p)*257 + k];
                    gr  += X.x*a.x - X.y*a.y;  gi  += X.x*a.y + X.y*a.x;
                    ur_ += X.x*b.x - X.y*b.y;  ui_ += X.x*b.y + X.y*b.x;
                }
                wk[swz(k)] = make_float2(gr - ui_, gi + ur_);
                if (k != 0 && k != 256)
                    wk[swz(512 - k)] = make_float2(gr + ui_, ur_ - gi);
            }
        }
    };

    // ---- P2: 5 packed q-pairs {2j,2j+1} + single q=10.
    //      Z accumulator [4 p][4 u] complex; Nyquist packed into Zi[p][0]
    //      (Z[0] and Z[256] are real for real output blocks). ----
    float Zr[4][4] = {{0.f}}, Zi[4][4] = {{0.f}};
    float ha[8];

#pragma unroll 1
    for (int pr = 0; pr < 6; ++pr) {
        const int qa = 2 * pr;
        einsum_gu(qa);
        fft512_r8<true>(wk, t, T);            // z = g + i*u for qa
#pragma unroll
        for (int u = 0; u < 8; ++u) {
            float2 v = wk[swz(t + 64*u)];
            ha[u] = v.x * v.y / (1.f + __expf(-v.x));      // h(qa) -> regs
        }
        if (pr < 5) {
            const int qb = qa + 1;
            einsum_gu(qb);
            fft512_r8<true>(wk, t, T);        // z = g + i*u for qb
#pragma unroll
            for (int u = 0; u < 8; ++u) {
                int n = t + 64*u;
                float2 v = wk[swz(n)];
                float hb = v.x * v.y / (1.f + __expf(-v.x));
                wk[swz(n)] = make_float2(ha[u], hb);       // pack h(qa)+i*h(qb)
            }
            fft512_r8<false>(wk, t, T);       // one FFT -> both H spectra
#pragma unroll
            for (int u = 0; u < 4; ++u) {
                int k = t + 64*u;             // k = 0..255
                float2 z = wk[swz(k)], m = wk[swz((512 - k) & 511)];
                float Har = 0.5f*(z.x + m.x), Hai = 0.5f*(z.y - m.y);
                float Hbr = 0.5f*(z.y + m.y), Hbi = 0.5f*(m.x - z.x);
                if (u == 0 && t == 0) {
                    // k=0 (Hai=Hbi=0 exact) real-only + Nyquist k=256
                    float2 ny = wk[swz(256)];    // (Ha256, Hb256), both real
#pragma unroll
                    for (int p = 0; p < 4; ++p) {
                        float2 da = Wd[(p*11 + qa)*257];
                        float2 db = Wd[(p*11 + qb)*257];
                        float2 na = Wd[(p*11 + qa)*257 + 256];
                        float2 nb = Wd[(p*11 + qb)*257 + 256];
                        Zr[p][0] += Har*da.x + Hbr*db.x;
                        Zi[p][0] += ny.x*na.x + ny.y*nb.x;   // Nyquist slot
                    }
                } else {
#pragma unroll
                    for (int p = 0; p < 4; ++p) {
                        float2 da = Wd[(p*11 + qa)*257 + k];
                        float2 db = Wd[(p*11 + qb)*257 + k];
                        Zr[p][u] += Har*da.x - Hai*da.y + Hbr*db.x - Hbi*db.y;
                        Zi[p][u] += Har*da.y + Hai*da.x + Hbr*db.y + Hbi*db.x;
                    }
                }
            }
        } else {
            // q = 10, unpacked real forward FFT
#pragma unroll
            for (int u = 0; u < 8; ++u)
                wk[swz(t + 64*u)] = make_float2(ha[u], 0.f);
            fft512_r8<false>(wk, t, T);
#pragma unroll
            for (int u = 0; u < 4; ++u) {
                int k = t + 64*u;
                float2 H = wk[swz(k)];
                if (u == 0 && t == 0) {
                    float H256 = wk[swz(256)].x;
#pragma unroll
                    for (int p = 0; p < 4; ++p) {
                        Zr[p][0] += H.x * Wd[(p*11 + 10)*257].x;
                        Zi[p][0] += H256 * Wd[(p*11 + 10)*257 + 256].x;
                    }
                } else {
#pragma unroll
                    for (int p = 0; p < 4; ++p) {
                        float2 d = Wd[(p*11 + 10)*257 + k];
                        Zr[p][u] += H.x*d.x - H.y*d.y;
                        Zi[p][u] += H.x*d.y + H.y*d.x;
                    }
                }
            }
        }
    }

    // ---- P3: two packed inverse FFTs (Z0+iZ1), (Z2+iZ3); fully unrolled ----
#pragma unroll
    for (int h = 0; h < 2; ++h) {
        const int pa = 2*h, pb = 2*h + 1;
        // u = 0: lane 0 writes k=0 and Nyquist from packed slots
        if (t == 0) {
            wk[swz(0)]   = make_float2(Zr[pa][0], Zr[pb][0]);
            wk[swz(256)] = make_float2(Zi[pa][0], Zi[pb][0]);
        } else {
            wk[swz(t)]       = make_float2(Zr[pa][0] - Zi[pb][0], Zi[pa][0] + Zr[pb][0]);
            wk[swz(512 - t)] = make_float2(Zr[pa][0] + Zi[pb][0], Zr[pb][0] - Zi[pa][0]);
        }
#pragma unroll
        for (int u = 1; u < 4; ++u) {
            int k = t + 64*u;   // 64..255, never 0/256
            wk[swz(k)]       = make_float2(Zr[pa][u] - Zi[pb][u], Zi[pa][u] + Zr[pb][u]);
            wk[swz(512 - k)] = make_float2(Zr[pa][u] + Zi[pb][u], Zr[pb][u] - Zi[pa][u]);
        }
        fft512_r8<true>(wk, t, T);
        float4* oa = (float4*)(out + row * 2048 + (size_t)pa * 512);
        float4* ob = (float4*)(out + row * 2048 + (size_t)pb * 512);
#pragma unroll
        for (int u = 0; u < 2; ++u) {
            int e = t + 64*u, n = 4*e;
            float2 v0 = wk[swz(n)],   v1 = wk[swz(n+1)];
            float2 v2 = wk[swz(n+2)], v3 = wk[swz(n+3)];
            oa[e] = make_float4(v0.x, v1.x, v2.x, v3.x);
            ob[e] = make_float4(v0.y, v1.y, v2.y, v3.y);
        }
    }
}

extern "C" void kernel_launch(void* const* d_in, const int* in_sizes, int n_in,
                              void* d_out, int out_size, void* d_ws, size_t ws_size,
                              hipStream_t stream)
{
    (void)n_in; (void)out_size; (void)ws_size;
    const float* x  = (const float*)d_in[0];
    const float* wg = (const float*)d_in[1];
    const float* wu = (const float*)d_in[2];
    const float* wd = (const float*)d_in[3];
    float2* wsp = (float2*)d_ws;          // 132*257 float2 = 271 KB used
    float*  out = (float*)d_out;

    const int rows = in_sizes[0] / 2048;  // 16384

    wf_prep<<<132, 64, 0, stream>>>(wg, wu, wd, wsp);
    bcffn<<<rows, 64, 0, stream>>>(x, wsp, out);
}

// Round 10
// 1073.708 us; speedup vs baseline: 1.2668x; 1.2668x over previous
//
#include <hip/hip_runtime.h>
#include <math.h>

// Block-circulant SwiGLU FFN via per-wave radix-8 FFT-512 (CirCNN style).
// d_model=2048 (p=4 blocks), d_ff=5632 (q=11 blocks), BLOCK=512.
// Round-10: R8/R9 one-wave-per-row structure; VGPR diet done HONESTLY:
//   * twiddle table (28 VGPR) -> 4 base values + in-register power iteration
//   * plain __launch_bounds__(64) -- NO min-waves cap (R9's forced-64 spilled)
//   * Z Nyquist packing kept ([4][4] complex, k=256 in Zi[*][0])
// Fenceless FFT: same-wave DS ops are in-order (HW-verified R4/R7).

// LDS element-index swizzle: every access pattern used here is GF(2)-linear
// rank-4 in lane bits -> uniform 4 lanes per bank pair (b64 minimum).
__device__ __forceinline__ int swz(int n) { return n ^ ((n >> 3) & 15); }

// 8-point DFT (DIF): A_m = sum_q a_q w8^{qm}, w8 = e^{-2pi i/8} (conj if INV).
template<bool INV>
__device__ __forceinline__ void dft8(float xr[8], float xi[8])
{
    const float C = 0.70710678118654752f;
    float tr[4], ti[4], ur[4], ui[4];
#pragma unroll
    for (int q = 0; q < 4; ++q) {
        tr[q] = xr[q] + xr[q+4];  ti[q] = xi[q] + xi[q+4];
        ur[q] = xr[q] - xr[q+4];  ui[q] = xi[q] - xi[q+4];
    }
    {
        float xx = ur[1], yy = ui[1];
        if (!INV) { ur[1] = C*(xx+yy); ui[1] = C*(yy-xx); }
        else      { ur[1] = C*(xx-yy); ui[1] = C*(xx+yy); }
    }
    {
        float xx = ur[2], yy = ui[2];
        if (!INV) { ur[2] = yy;  ui[2] = -xx; }
        else      { ur[2] = -yy; ui[2] = xx; }
    }
    {
        float xx = ur[3], yy = ui[3];
        if (!INV) { ur[3] = C*(yy-xx);  ui[3] = -C*(xx+yy); }
        else      { ur[3] = -C*(xx+yy); ui[3] = C*(xx-yy); }
    }
    {
        float s0r=tr[0]+tr[2], s0i=ti[0]+ti[2];
        float d0r=tr[0]-tr[2], d0i=ti[0]-ti[2];
        float s1r=tr[1]+tr[3], s1i=ti[1]+ti[3];
        float e1r=tr[1]-tr[3], e1i=ti[1]-ti[3];
        float d1r, d1i;
        if (!INV) { d1r = e1i;  d1i = -e1r; } else { d1r = -e1i; d1i = e1r; }
        xr[0]=s0r+s1r; xi[0]=s0i+s1i;
        xr[2]=d0r+d1r; xi[2]=d0i+d1i;
        xr[4]=s0r-s1r; xi[4]=s0i-s1i;
        xr[6]=d0r-d1r; xi[6]=d0i-d1i;
    }
    {
        float s0r=ur[0]+ur[2], s0i=ui[0]+ui[2];
        float d0r=ur[0]-ur[2], d0i=ui[0]-ui[2];
        float s1r=ur[1]+ur[3], s1i=ui[1]+ui[3];
        float e1r=ur[1]-ur[3], e1i=ui[1]-ui[3];
        float d1r, d1i;
        if (!INV) { d1r = e1i;  d1i = -e1r; } else { d1r = -e1i; d1i = e1r; }
        xr[1]=s0r+s1r; xi[1]=s0i+s1i;
        xr[3]=d0r+d1r; xi[3]=d0i+d1i;
        xr[5]=s0r-s1r; xi[5]=s0i-s1i;
        xr[7]=d0r-d1r; xi[7]=d0i-d1i;
    }
}

// In-place radix-8 Stockham FFT-512 on a wave-private (swizzled) LDS buffer.
// Natural-order in/out; forward = e^{-i}, INV = conjugated (unscaled inverse).
// Twiddles: base rotations (c0,s0)=W512^l, (c1,s1)=W64^(l>>3) passed in;
// powers m=1..7 generated by in-register iteration (saves 24 VGPR vs table).
template<bool INV>
__device__ __forceinline__ void fft512_r8(float2* wk, int l,
                                          float c0, float s0, float c1, float s1)
{
    const float S0 = INV ? -s0 : s0;
    const float S1 = INV ? -s1 : s1;
    float xr[8], xi[8];
    // ---- stage 0 (s=1): twiddle W512^{l*m} ----
#pragma unroll
    for (int q = 0; q < 8; ++q) { float2 v = wk[swz(l + 64*q)]; xr[q]=v.x; xi[q]=v.y; }
    dft8<INV>(xr, xi);
    {
        float wr = c0, wi = S0;
#pragma unroll
        for (int m = 1; m < 8; ++m) {
            float nr = xr[m]*wr - xi[m]*wi, ni = xr[m]*wi + xi[m]*wr;
            xr[m]=nr; xi[m]=ni;
            float tw = wr*c0 - wi*S0;  wi = wr*S0 + wi*c0;  wr = tw;
        }
    }
#pragma unroll
    for (int m = 0; m < 8; ++m) wk[swz(8*l + m)] = make_float2(xr[m], xi[m]);
    // ---- stage 1 (s=8): twiddle W64^{(l>>3)*m} ----
#pragma unroll
    for (int q = 0; q < 8; ++q) { float2 v = wk[swz(l + 64*q)]; xr[q]=v.x; xi[q]=v.y; }
    dft8<INV>(xr, xi);
    {
        float wr = c1, wi = S1;
#pragma unroll
        for (int m = 1; m < 8; ++m) {
            float nr = xr[m]*wr - xi[m]*wi, ni = xr[m]*wi + xi[m]*wr;
            xr[m]=nr; xi[m]=ni;
            float tw = wr*c1 - wi*S1;  wi = wr*S1 + wi*c1;  wr = tw;
        }
    }
    {
        const int base = 64*(l>>3) + (l&7);
#pragma unroll
        for (int m = 0; m < 8; ++m) wk[swz(base + 8*m)] = make_float2(xr[m], xi[m]);
    }
    // ---- stage 2 (s=64): no twiddle ----
#pragma unroll
    for (int q = 0; q < 8; ++q) { float2 v = wk[swz(l + 64*q)]; xr[q]=v.x; xi[q]=v.y; }
    dft8<INV>(xr, xi);
#pragma unroll
    for (int m = 0; m < 8; ++m) wk[swz(l + 64*m)] = make_float2(xr[m], xi[m]);
}

// ---------------- weight spectra precompute: one wave per weight block ----------------
// wsp (float2): blocks 0..43 = rfft(wg)/512 (idx q*4+p), 44..87 = rfft(wu)/512,
// 88..131 = rfft(wd)/512 (idx p*11+q). 257 entries per block.
__global__ __launch_bounds__(64) void wf_prep(const float* __restrict__ wg,
                                              const float* __restrict__ wu,
                                              const float* __restrict__ wd,
                                              float2* __restrict__ wsp)
{
    __shared__ float2 wk[512];
    const int t = threadIdx.x;
    float c0, s0, c1, s1;
    __sincosf(-6.283185307179586f * (float)t * (1.0f/512.0f), &s0, &c0);
    __sincosf(-6.283185307179586f * (float)(t >> 3) * (1.0f/64.0f), &s1, &c1);
    const int b = blockIdx.x;      // 0..131
    const float* src = (b < 44) ? (wg + (size_t)b * 512)
                     : (b < 88) ? (wu + (size_t)(b - 44) * 512)
                                : (wd + (size_t)(b - 88) * 512);
    float2* dst = wsp + (size_t)b * 257;

#pragma unroll
    for (int i = 0; i < 8; ++i) { int n = t + 64*i; wk[swz(n)] = make_float2(src[n], 0.f); }
    fft512_r8<false>(wk, t, c0, s0, c1, s1);
    const float sc = 1.0f / 512.0f;   // fold irfft 1/N into the weight spectrum
#pragma unroll
    for (int i = 0; i < 5; ++i) {
        int k = t + 64*i;
        if (k <= 256) { float2 z = wk[swz(k)]; dst[k] = make_float2(sc*z.x, sc*z.y); }
    }
}

// ---------------- fused FFN: ONE 64-thread block (one wave) per row ----------------
__global__ __launch_bounds__(64) void bcffn(const float* __restrict__ x,
                                            const float2* __restrict__ wsp,
                                            float* __restrict__ out)
{
    __shared__ float2 wk[512];        //  4 KB   FFT work buffer (swizzled)
    __shared__ float2 sXf[4][257];    //  8.2 KB X spectra (half, Hermitian)

    const int t = threadIdx.x;
    const size_t row = blockIdx.x;

    float c0, s0, c1, s1;
    __sincosf(-6.283185307179586f * (float)t * (1.0f/512.0f), &s0, &c0);
    __sincosf(-6.283185307179586f * (float)(t >> 3) * (1.0f/64.0f), &s1, &c1);

    const float2* Wg = wsp;
    const float2* Wu = wsp + 44 * 257;
    const float2* Wd = wsp + 88 * 257;

    // ---- P1: two packed FFTs: (x block 0 + i x block 1), (block 2 + i block 3) ----
#pragma unroll 1
    for (int h = 0; h < 2; ++h) {
        const float4* xa = (const float4*)(x + row * 2048 + (size_t)(2*h)   * 512);
        const float4* xb = (const float4*)(x + row * 2048 + (size_t)(2*h+1) * 512);
#pragma unroll
        for (int u = 0; u < 2; ++u) {
            int e = t + 64*u;
            float4 a = xa[e], b = xb[e];
            int n = 4*e;
            wk[swz(n+0)] = make_float2(a.x, b.x);
            wk[swz(n+1)] = make_float2(a.y, b.y);
            wk[swz(n+2)] = make_float2(a.z, b.z);
            wk[swz(n+3)] = make_float2(a.w, b.w);
        }
        fft512_r8<false>(wk, t, c0, s0, c1, s1);
#pragma unroll
        for (int u = 0; u < 5; ++u) {
            int k = t + 64*u;
            if (k <= 256) {
                float2 z = wk[swz(k)], m = wk[swz((512 - k) & 511)];
                sXf[2*h][k]   = make_float2(0.5f*(z.x + m.x), 0.5f*(z.y - m.y));
                sXf[2*h+1][k] = make_float2(0.5f*(z.y + m.y), 0.5f*(m.x - z.x));
            }
        }
    }

    // einsum for block-row q: packed spectrum Z = G + i*U into wk (all 512)
    auto einsum_gu = [&](int q) {
#pragma unroll
        for (int u = 0; u < 5; ++u) {
            int k = t + 64*u;
            if (k <= 256) {
                float gr=0.f, gi=0.f, ur_=0.f, ui_=0.f;
#pragma unroll
                for (int p = 0; p < 4; ++p) {
                    float2 X = sXf[p][k];
                    float2 a = Wg[(q*4 + p)*257 + k];
                    float2 b = Wu[(q*4 + p)*257 + k];
                    gr  += X.x*a.x - X.y*a.y;  gi  += X.x*a.y + X.y*a.x;
                    ur_ += X.x*b.x - X.y*b.y;  ui_ += X.x*b.y + X.y*b.x;
                }
                wk[swz(k)] = make_float2(gr - ui_, gi + ur_);
                if (k != 0 && k != 256)
                    wk[swz(512 - k)] = make_float2(gr + ui_, ur_ - gi);
            }
        }
    };

    // ---- P2: 5 packed q-pairs {2j,2j+1} + single q=10.
    //      Z accumulator [4 p][4 u] complex; Nyquist packed into Zi[p][0]. ----
    float Zr[4][4] = {{0.f}}, Zi[4][4] = {{0.f}};
    float ha[8];

#pragma unroll 1
    for (int pr = 0; pr < 6; ++pr) {
        const int qa = 2 * pr;
        einsum_gu(qa);
        fft512_r8<true>(wk, t, c0, s0, c1, s1);       // z = g + i*u for qa
#pragma unroll
        for (int u = 0; u < 8; ++u) {
            float2 v = wk[swz(t + 64*u)];
            ha[u] = v.x * v.y / (1.f + __expf(-v.x));  // h(qa) -> regs
        }
        if (pr < 5) {
            const int qb = qa + 1;
            einsum_gu(qb);
            fft512_r8<true>(wk, t, c0, s0, c1, s1);   // z = g + i*u for qb
#pragma unroll
            for (int u = 0; u < 8; ++u) {
                int n = t + 64*u;
                float2 v = wk[swz(n)];
                float hb = v.x * v.y / (1.f + __expf(-v.x));
                wk[swz(n)] = make_float2(ha[u], hb);   // pack h(qa)+i*h(qb)
            }
            fft512_r8<false>(wk, t, c0, s0, c1, s1);  // one FFT -> both H spectra
#pragma unroll
            for (int u = 0; u < 4; ++u) {
                int k = t + 64*u;             // k = 0..255
                float2 z = wk[swz(k)], m = wk[swz((512 - k) & 511)];
                float Har = 0.5f*(z.x + m.x), Hai = 0.5f*(z.y - m.y);
                float Hbr = 0.5f*(z.y + m.y), Hbi = 0.5f*(m.x - z.x);
                if (u == 0 && t == 0) {
                    // k=0 (Hai=Hbi=0 exact) real-only + Nyquist k=256
                    float2 ny = wk[swz(256)];    // (Ha256, Hb256), both real
#pragma unroll
                    for (int p = 0; p < 4; ++p) {
                        float2 da = Wd[(p*11 + qa)*257];
                        float2 db = Wd[(p*11 + qb)*257];
                        float2 na = Wd[(p*11 + qa)*257 + 256];
                        float2 nb = Wd[(p*11 + qb)*257 + 256];
                        Zr[p][0] += Har*da.x + Hbr*db.x;
                        Zi[p][0] += ny.x*na.x + ny.y*nb.x;   // Nyquist slot
                    }
                } else {
#pragma unroll
                    for (int p = 0; p < 4; ++p) {
                        float2 da = Wd[(p*11 + qa)*257 + k];
                        float2 db = Wd[(p*11 + qb)*257 + k];
                        Zr[p][u] += Har*da.x - Hai*da.y + Hbr*db.x - Hbi*db.y;
                        Zi[p][u] += Har*da.y + Hai*da.x + Hbr*db.y + Hbi*db.x;
                    }
                }
            }
        } else {
            // q = 10, unpacked real forward FFT
#pragma unroll
            for (int u = 0; u < 8; ++u)
                wk[swz(t + 64*u)] = make_float2(ha[u], 0.f);
            fft512_r8<false>(wk, t, c0, s0, c1, s1);
#pragma unroll
            for (int u = 0; u < 4; ++u) {
                int k = t + 64*u;
                float2 H = wk[swz(k)];
                if (u == 0 && t == 0) {
                    float H256 = wk[swz(256)].x;
#pragma unroll
                    for (int p = 0; p < 4; ++p) {
                        Zr[p][0] += H.x * Wd[(p*11 + 10)*257].x;
                        Zi[p][0] += H256 * Wd[(p*11 + 10)*257 + 256].x;
                    }
                } else {
#pragma unroll
                    for (int p = 0; p < 4; ++p) {
                        float2 d = Wd[(p*11 + 10)*257 + k];
                        Zr[p][u] += H.x*d.x - H.y*d.y;
                        Zi[p][u] += H.x*d.y + H.y*d.x;
                    }
                }
            }
        }
    }

    // ---- P3: two packed inverse FFTs (Z0+iZ1), (Z2+iZ3); fully unrolled ----
#pragma unroll
    for (int h = 0; h < 2; ++h) {
        const int pa = 2*h, pb = 2*h + 1;
        // u = 0: lane 0 writes k=0 and Nyquist from packed slots
        if (t == 0) {
            wk[swz(0)]   = make_float2(Zr[pa][0], Zr[pb][0]);
            wk[swz(256)] = make_float2(Zi[pa][0], Zi[pb][0]);
        } else {
            wk[swz(t)]       = make_float2(Zr[pa][0] - Zi[pb][0], Zi[pa][0] + Zr[pb][0]);
            wk[swz(512 - t)] = make_float2(Zr[pa][0] + Zi[pb][0], Zr[pb][0] - Zi[pa][0]);
        }
#pragma unroll
        for (int u = 1; u < 4; ++u) {
            int k = t + 64*u;   // 64..255, never 0/256
            wk[swz(k)]       = make_float2(Zr[pa][u] - Zi[pb][u], Zi[pa][u] + Zr[pb][u]);
            wk[swz(512 - k)] = make_float2(Zr[pa][u] + Zi[pb][u], Zr[pb][u] - Zi[pa][u]);
        }
        fft512_r8<true>(wk, t, c0, s0, c1, s1);
        float4* oa = (float4*)(out + row * 2048 + (size_t)pa * 512);
        float4* ob = (float4*)(out + row * 2048 + (size_t)pb * 512);
#pragma unroll
        for (int u = 0; u < 2; ++u) {
            int e = t + 64*u, n = 4*e;
            float2 v0 = wk[swz(n)],   v1 = wk[swz(n+1)];
            float2 v2 = wk[swz(n+2)], v3 = wk[swz(n+3)];
            oa[e] = make_float4(v0.x, v1.x, v2.x, v3.x);
            ob[e] = make_float4(v0.y, v1.y, v2.y, v3.y);
        }
    }
}

extern "C" void kernel_launch(void* const* d_in, const int* in_sizes, int n_in,
                              void* d_out, int out_size, void* d_ws, size_t ws_size,
                              hipStream_t stream)
{
    (void)n_in; (void)out_size; (void)ws_size;
    const float* x  = (const float*)d_in[0];
    const float* wg = (const float*)d_in[1];
    const float* wu = (const float*)d_in[2];
    const float* wd = (const float*)d_in[3];
    float2* wsp = (float2*)d_ws;          // 132*257 float2 = 271 KB used
    float*  out = (float*)d_out;

    const int rows = in_sizes[0] / 2048;  // 16384

    wf_prep<<<132, 64, 0, stream>>>(wg, wu, wd, wsp);
    bcffn<<<rows, 64, 0, stream>>>(x, wsp, out);
}

// Round 11
// 554.109 us; speedup vs baseline: 2.4546x; 1.9377x over previous
//
#include <hip/hip_runtime.h>
#include <math.h>

// Block-circulant SwiGLU FFN via per-wave radix-8 FFT-512 (CirCNN style).
// d_model=2048 (p=4 blocks), d_ff=5632 (q=11 blocks), BLOCK=512.
// Round-11: R7 base (4-wave block/row, fenceless, table twiddles, 550us) +
// ONE change: in-register FUSION of iFFT-end -> silu -> fFFT-start.
//   fft512_r8_head: S0,S1 in LDS; S2 dft8 ends in REGISTERS (no write).
//   fft512_r8_tail: S0 dft8+twiddle from REGISTERS; S1,S2 in LDS.
// Eliminates 4 LDS round-trips through identical addresses per fused
// boundary (~21% of per-row DS ops) with bit-identical arithmetic.
// Fenceless safety: same-wave DS ops are in-order (HW-verified R4/R7).

// LDS element-index swizzle: every access pattern used here is GF(2)-linear
// rank-4 in lane bits -> uniform 4 lanes per bank pair (b64 minimum).
__device__ __forceinline__ int swz(int n) { return n ^ ((n >> 3) & 15); }

struct Tw { float t0r[7], t0i[7], t1r[7], t1i[7]; };

// Per-lane register twiddles: stage0 W512^{l*m}, stage1 W512^{8*(l>>3)*m}.
__device__ __forceinline__ void make_tw(int l, Tw& T)
{
    float c0, s0;
    __sincosf(-6.283185307179586f * (float)l * (1.0f/512.0f), &s0, &c0);
    float pr = c0, pi = s0;
    T.t0r[0] = pr; T.t0i[0] = pi;
#pragma unroll
    for (int m = 1; m < 7; ++m) {
        float nr = pr*c0 - pi*s0, ni = pr*s0 + pi*c0;
        pr = nr; pi = ni;
        T.t0r[m] = pr; T.t0i[m] = pi;
    }
    float c1, s1;
    __sincosf(-6.283185307179586f * (float)(l >> 3) * (1.0f/64.0f), &s1, &c1);
    pr = c1; pi = s1;
    T.t1r[0] = pr; T.t1i[0] = pi;
#pragma unroll
    for (int m = 1; m < 7; ++m) {
        float nr = pr*c1 - pi*s1, ni = pr*s1 + pi*c1;
        pr = nr; pi = ni;
        T.t1r[m] = pr; T.t1i[m] = pi;
    }
}

// 8-point DFT (DIF): A_m = sum_q a_q w8^{qm}, w8 = e^{-2pi i/8} (conj if INV).
template<bool INV>
__device__ __forceinline__ void dft8(float xr[8], float xi[8])
{
    const float C = 0.70710678118654752f;
    float tr[4], ti[4], ur[4], ui[4];
#pragma unroll
    for (int q = 0; q < 4; ++q) {
        tr[q] = xr[q] + xr[q+4];  ti[q] = xi[q] + xi[q+4];
        ur[q] = xr[q] - xr[q+4];  ui[q] = xi[q] - xi[q+4];
    }
    {
        float xx = ur[1], yy = ui[1];
        if (!INV) { ur[1] = C*(xx+yy); ui[1] = C*(yy-xx); }
        else      { ur[1] = C*(xx-yy); ui[1] = C*(xx+yy); }
    }
    {
        float xx = ur[2], yy = ui[2];
        if (!INV) { ur[2] = yy;  ui[2] = -xx; }
        else      { ur[2] = -yy; ui[2] = xx; }
    }
    {
        float xx = ur[3], yy = ui[3];
        if (!INV) { ur[3] = C*(yy-xx);  ui[3] = -C*(xx+yy); }
        else      { ur[3] = -C*(xx+yy); ui[3] = C*(xx-yy); }
    }
    {
        float s0r=tr[0]+tr[2], s0i=ti[0]+ti[2];
        float d0r=tr[0]-tr[2], d0i=ti[0]-ti[2];
        float s1r=tr[1]+tr[3], s1i=ti[1]+ti[3];
        float e1r=tr[1]-tr[3], e1i=ti[1]-ti[3];
        float d1r, d1i;
        if (!INV) { d1r = e1i;  d1i = -e1r; } else { d1r = -e1i; d1i = e1r; }
        xr[0]=s0r+s1r; xi[0]=s0i+s1i;
        xr[2]=d0r+d1r; xi[2]=d0i+d1i;
        xr[4]=s0r-s1r; xi[4]=s0i-s1i;
        xr[6]=d0r-d1r; xi[6]=d0i-d1i;
    }
    {
        float s0r=ur[0]+ur[2], s0i=ui[0]+ui[2];
        float d0r=ur[0]-ur[2], d0i=ui[0]-ui[2];
        float s1r=ur[1]+ur[3], s1i=ui[1]+ui[3];
        float e1r=ur[1]-ur[3], e1i=ui[1]-ui[3];
        float d1r, d1i;
        if (!INV) { d1r = e1i;  d1i = -e1r; } else { d1r = -e1i; d1i = e1r; }
        xr[1]=s0r+s1r; xi[1]=s0i+s1i;
        xr[3]=d0r+d1r; xi[3]=d0i+d1i;
        xr[5]=s0r-s1r; xi[5]=s0i-s1i;
        xr[7]=d0r-d1r; xi[7]=d0i-d1i;
    }
}

// Twiddle helper: x[m] *= T^m for m=1..7 (conjugated if INV).
template<bool INV>
__device__ __forceinline__ void twiddle7(float xr[8], float xi[8],
                                         const float* tr, const float* ti)
{
#pragma unroll
    for (int m = 1; m < 8; ++m) {
        float wr = tr[m-1], wi = INV ? -ti[m-1] : ti[m-1];
        float nr = xr[m]*wr - xi[m]*wi, ni = xr[m]*wi + xi[m]*wr;
        xr[m]=nr; xi[m]=ni;
    }
}

// Full in-place radix-8 Stockham FFT-512 (natural order in/out).
template<bool INV>
__device__ __forceinline__ void fft512_r8(float2* wk, int l, const Tw& T)
{
    float xr[8], xi[8];
#pragma unroll
    for (int q = 0; q < 8; ++q) { float2 v = wk[swz(l + 64*q)]; xr[q]=v.x; xi[q]=v.y; }
    dft8<INV>(xr, xi);
    twiddle7<INV>(xr, xi, T.t0r, T.t0i);
#pragma unroll
    for (int m = 0; m < 8; ++m) wk[swz(8*l + m)] = make_float2(xr[m], xi[m]);
#pragma unroll
    for (int q = 0; q < 8; ++q) { float2 v = wk[swz(l + 64*q)]; xr[q]=v.x; xi[q]=v.y; }
    dft8<INV>(xr, xi);
    twiddle7<INV>(xr, xi, T.t1r, T.t1i);
    {
        const int base = 64*(l>>3) + (l&7);
#pragma unroll
        for (int m = 0; m < 8; ++m) wk[swz(base + 8*m)] = make_float2(xr[m], xi[m]);
    }
#pragma unroll
    for (int q = 0; q < 8; ++q) { float2 v = wk[swz(l + 64*q)]; xr[q]=v.x; xi[q]=v.y; }
    dft8<INV>(xr, xi);
#pragma unroll
    for (int m = 0; m < 8; ++m) wk[swz(l + 64*m)] = make_float2(xr[m], xi[m]);
}

// HEAD: stages 0,1 in LDS; stage 2 dft8 ends in REGISTERS (no final write).
// On return xr[m], xi[m] = element (l + 64*m) of the transform result.
template<bool INV>
__device__ __forceinline__ void fft512_r8_head(float2* wk, int l, const Tw& T,
                                               float xr[8], float xi[8])
{
#pragma unroll
    for (int q = 0; q < 8; ++q) { float2 v = wk[swz(l + 64*q)]; xr[q]=v.x; xi[q]=v.y; }
    dft8<INV>(xr, xi);
    twiddle7<INV>(xr, xi, T.t0r, T.t0i);
#pragma unroll
    for (int m = 0; m < 8; ++m) wk[swz(8*l + m)] = make_float2(xr[m], xi[m]);
#pragma unroll
    for (int q = 0; q < 8; ++q) { float2 v = wk[swz(l + 64*q)]; xr[q]=v.x; xi[q]=v.y; }
    dft8<INV>(xr, xi);
    twiddle7<INV>(xr, xi, T.t1r, T.t1i);
    {
        const int base = 64*(l>>3) + (l&7);
#pragma unroll
        for (int m = 0; m < 8; ++m) wk[swz(base + 8*m)] = make_float2(xr[m], xi[m]);
    }
#pragma unroll
    for (int q = 0; q < 8; ++q) { float2 v = wk[swz(l + 64*q)]; xr[q]=v.x; xi[q]=v.y; }
    dft8<INV>(xr, xi);            // results stay in regs: element l+64m in slot m
}

// TAIL: stage 0 dft8+twiddle from REGISTERS (input xr[q] = element l+64q);
// stages 1,2 in LDS; full natural-order result written to wk.
template<bool INV>
__device__ __forceinline__ void fft512_r8_tail(float2* wk, int l, const Tw& T,
                                               float xr[8], float xi[8])
{
    dft8<INV>(xr, xi);
    twiddle7<INV>(xr, xi, T.t0r, T.t0i);
#pragma unroll
    for (int m = 0; m < 8; ++m) wk[swz(8*l + m)] = make_float2(xr[m], xi[m]);
#pragma unroll
    for (int q = 0; q < 8; ++q) { float2 v = wk[swz(l + 64*q)]; xr[q]=v.x; xi[q]=v.y; }
    dft8<INV>(xr, xi);
    twiddle7<INV>(xr, xi, T.t1r, T.t1i);
    {
        const int base = 64*(l>>3) + (l&7);
#pragma unroll
        for (int m = 0; m < 8; ++m) wk[swz(base + 8*m)] = make_float2(xr[m], xi[m]);
    }
#pragma unroll
    for (int q = 0; q < 8; ++q) { float2 v = wk[swz(l + 64*q)]; xr[q]=v.x; xi[q]=v.y; }
    dft8<INV>(xr, xi);
#pragma unroll
    for (int m = 0; m < 8; ++m) wk[swz(l + 64*m)] = make_float2(xr[m], xi[m]);
}

// ---------------- weight spectra precompute: one wave per weight block ----------------
// wsp (float2): blocks 0..43 = rfft(wg)/512 (idx q*4+p), 44..87 = rfft(wu)/512,
// 88..131 = rfft(wd)/512 (idx p*11+q). 257 entries per block.
__global__ __launch_bounds__(64) void wf_prep(const float* __restrict__ wg,
                                              const float* __restrict__ wu,
                                              const float* __restrict__ wd,
                                              float2* __restrict__ wsp)
{
    __shared__ float2 wk[512];
    const int t = threadIdx.x;
    Tw T; make_tw(t, T);
    const int b = blockIdx.x;      // 0..131
    const float* src = (b < 44) ? (wg + (size_t)b * 512)
                     : (b < 88) ? (wu + (size_t)(b - 44) * 512)
                                : (wd + (size_t)(b - 88) * 512);
    float2* dst = wsp + (size_t)b * 257;

#pragma unroll
    for (int i = 0; i < 8; ++i) { int n = t + 64*i; wk[swz(n)] = make_float2(src[n], 0.f); }
    fft512_r8<false>(wk, t, T);
    const float sc = 1.0f / 512.0f;   // fold irfft 1/N into the weight spectrum
#pragma unroll
    for (int i = 0; i < 5; ++i) {
        int k = t + 64*i;
        if (k <= 256) { float2 z = wk[swz(k)]; dst[k] = make_float2(sc*z.x, sc*z.y); }
    }
}

// ---------------- fused FFN: one 256-thread block per row ----------------
__global__ __launch_bounds__(256) void bcffn(const float* __restrict__ x,
                                             const float2* __restrict__ wsp,
                                             float* __restrict__ out)
{
    __shared__ float2 sWork[4 * 512];   // 16 KB    per-wave FFT buffers (swizzled)
    __shared__ float2 sXf[4][257];      //  8.2 KB  X spectra; reused as Z scratch in P3
    __shared__ float2 sHf[11][257];     // 22.6 KB  H spectra
                                        // ~46.9 KB -> 3 blocks/CU

    const int tid = threadIdx.x;
    const int t = tid & 63, w = tid >> 6;
    const size_t row = blockIdx.x;

    Tw T; make_tw(t, T);

    const float2* Wg = wsp;
    const float2* Wu = wsp + 44 * 257;
    const float2* Wd = wsp + 88 * 257;

    float2* wk = sWork + (w << 9);

    // ---- P1: waves 0,1: packed FFT of (x block 2w) + i*(x block 2w+1) ----
    if (w < 2) {
        const float4* xa = (const float4*)(x + row * 2048 + (size_t)(2*w)   * 512);
        const float4* xb = (const float4*)(x + row * 2048 + (size_t)(2*w+1) * 512);
#pragma unroll
        for (int u = 0; u < 2; ++u) {
            int e = t + 64*u;
            float4 a = xa[e], b = xb[e];
            int n = 4*e;
            wk[swz(n+0)] = make_float2(a.x, b.x);
            wk[swz(n+1)] = make_float2(a.y, b.y);
            wk[swz(n+2)] = make_float2(a.z, b.z);
            wk[swz(n+3)] = make_float2(a.w, b.w);
        }
        fft512_r8<false>(wk, t, T);
#pragma unroll
        for (int u = 0; u < 5; ++u) {
            int k = t + 64*u;
            if (k <= 256) {
                float2 z = wk[swz(k)], m = wk[swz((512 - k) & 511)];
                sXf[2*w][k]   = make_float2(0.5f*(z.x + m.x), 0.5f*(z.y - m.y));
                sXf[2*w+1][k] = make_float2(0.5f*(z.y + m.y), 0.5f*(m.x - z.x));
            }
        }
    }
    __syncthreads();

    // einsum for block-row q: packed spectrum Z = G + i*U into wk (all 512)
    auto einsum_gu = [&](int q) {
#pragma unroll
        for (int u = 0; u < 5; ++u) {
            int k = t + 64*u;
            if (k <= 256) {
                float gr=0.f, gi=0.f, ur_=0.f, ui_=0.f;
#pragma unroll
                for (int p = 0; p < 4; ++p) {
                    float2 X = sXf[p][k];
                    float2 a = Wg[(q*4 + p)*257 + k];
                    float2 b = Wu[(q*4 + p)*257 + k];
                    gr  += X.x*a.x - X.y*a.y;  gi  += X.x*a.y + X.y*a.x;
                    ur_ += X.x*b.x - X.y*b.y;  ui_ += X.x*b.y + X.y*b.x;
                }
                wk[swz(k)] = make_float2(gr - ui_, gi + ur_);
                if (k != 0 && k != 256)
                    wk[swz(512 - k)] = make_float2(gr + ui_, ur_ - gi);
            }
        }
    };

    // ---- P2: q-pair (qa=w, qb=w+4) with FUSED iFFT->silu->fFFT; leftover qc=w+8 ----
    {
        const int qa = w, qb = w + 4;
        float har[8];
        float xr[8], xi[8];

        einsum_gu(qa);
        fft512_r8_head<true>(wk, t, T, xr, xi);     // z(qa) = g + i*u in regs
#pragma unroll
        for (int u = 0; u < 8; ++u)
            har[u] = xr[u] * xi[u] / (1.f + __expf(-xr[u]));   // h(qa) in regs

        einsum_gu(qb);
        fft512_r8_head<true>(wk, t, T, xr, xi);     // z(qb) = g + i*u in regs
#pragma unroll
        for (int u = 0; u < 8; ++u) {
            float hb = xr[u] * xi[u] / (1.f + __expf(-xr[u]));
            xr[u] = har[u];  xi[u] = hb;            // pack h(qa)+i*h(qb) in regs
        }
        fft512_r8_tail<false>(wk, t, T, xr, xi);    // fFFT, S0 from regs
#pragma unroll
        for (int u = 0; u < 5; ++u) {
            int k = t + 64*u;
            if (k <= 256) {
                float2 z = wk[swz(k)], m = wk[swz((512 - k) & 511)];
                sHf[qa][k] = make_float2(0.5f*(z.x + m.x), 0.5f*(z.y - m.y));
                sHf[qb][k] = make_float2(0.5f*(z.y + m.y), 0.5f*(m.x - z.x));
            }
        }

        if (w < 3) {
            const int qc = w + 8;
            einsum_gu(qc);
            fft512_r8_head<true>(wk, t, T, xr, xi);
#pragma unroll
            for (int u = 0; u < 8; ++u) {
                xr[u] = xr[u] * xi[u] / (1.f + __expf(-xr[u]));
                xi[u] = 0.f;
            }
            fft512_r8_tail<false>(wk, t, T, xr, xi);
#pragma unroll
            for (int u = 0; u < 5; ++u) {
                int k = t + 64*u;
                if (k <= 256) sHf[qc][k] = wk[swz(k)];
            }
        }
    }
    __syncthreads();

    // ---- P3: all waves einsum Z_{p=w}; waves 2,3 publish to scratch;
    //      waves 0,1 pack (Z_w + i*Z_{w+2}) -> one iFFT -> two output blocks ----
    float Zr[5] = {0.f,0.f,0.f,0.f,0.f};
    float Zi[5] = {0.f,0.f,0.f,0.f,0.f};
#pragma unroll
    for (int u = 0; u < 5; ++u) {
        int k = t + 64*u;
        if (k <= 256) {
            float zr = 0.f, zi = 0.f;
#pragma unroll
            for (int q = 0; q < 11; ++q) {
                float2 H = sHf[q][k];
                float2 d = Wd[(w*11 + q)*257 + k];
                zr += H.x*d.x - H.y*d.y;
                zi += H.x*d.y + H.y*d.x;
            }
            Zr[u] = zr; Zi[u] = zi;
        }
    }
    if (w >= 2) {       // publish Z_p2 -> sXf[0], Z_p3 -> sXf[1] (sXf reads all done)
#pragma unroll
        for (int u = 0; u < 5; ++u) {
            int k = t + 64*u;
            if (k <= 256) sXf[w-2][k] = make_float2(Zr[u], Zi[u]);
        }
    }
    __syncthreads();
    if (w < 2) {
#pragma unroll
        for (int u = 0; u < 5; ++u) {
            int k = t + 64*u;
            if (k <= 256) {
                float2 zb = sXf[w][k];          // partner spectrum Z_{w+2}
                wk[swz(k)] = make_float2(Zr[u] - zb.y, Zi[u] + zb.x);
                if (k != 0 && k != 256)
                    wk[swz(512 - k)] = make_float2(Zr[u] + zb.y, zb.x - Zi[u]);
            }
        }
        fft512_r8<true>(wk, t, T);
        float4* oa = (float4*)(out + row * 2048 + (size_t)w       * 512);
        float4* ob = (float4*)(out + row * 2048 + (size_t)(w + 2) * 512);
#pragma unroll
        for (int u = 0; u < 2; ++u) {
            int e = t + 64*u, n = 4*e;
            float2 v0 = wk[swz(n)],   v1 = wk[swz(n+1)];
            float2 v2 = wk[swz(n+2)], v3 = wk[swz(n+3)];
            oa[e] = make_float4(v0.x, v1.x, v2.x, v3.x);
            ob[e] = make_float4(v0.y, v1.y, v2.y, v3.y);
        }
    }
}

extern "C" void kernel_launch(void* const* d_in, const int* in_sizes, int n_in,
                              void* d_out, int out_size, void* d_ws, size_t ws_size,
                              hipStream_t stream)
{
    (void)n_in; (void)out_size; (void)ws_size;
    const float* x  = (const float*)d_in[0];
    const float* wg = (const float*)d_in[1];
    const float* wu = (const float*)d_in[2];
    const float* wd = (const float*)d_in[3];
    float2* wsp = (float2*)d_ws;          // 132*257 float2 = 271 KB used
    float*  out = (float*)d_out;

    const int rows = in_sizes[0] / 2048;  // 16384

    wf_prep<<<132, 64, 0, stream>>>(wg, wu, wd, wsp);
    bcffn<<<rows, 256, 0, stream>>>(x, wsp, out);
}